// Round 4
// baseline (205.457 us; speedup 1.0000x reference)
//
#include <hip/hip_runtime.h>
#include <hip/hip_bf16.h>

#define LL 2048
#define DM 512
#define SCALE 0.02209708691207961f   // 1/sqrt(2048)

typedef unsigned short u16;
typedef __attribute__((ext_vector_type(8))) short short8;    // 8 bf16 (4 VGPRs)
typedef __attribute__((ext_vector_type(4))) short short4v;   // 4 bf16 (b64)
typedef __attribute__((ext_vector_type(4))) float f32x4;     // MFMA C/D

// ws layout (u16 element offsets), total 22.68 MB (< proven 25.3 MB budget):
#define XQ_OFF 0u         // bf16 queries  [2][2048][512]
#define XK_OFF 2097152u   // bf16 keys     [2][2048][512]
#define WT_OFF 4194304u   // bf16 W^T      [3][8][64e][512d]
#define QB_OFF 4980736u   // bf16 Q proj   [16][2048][64]  (pre-scaled by SCALE)
#define KB_OFF 7077888u   // bf16 K proj   [16][2048][64]
#define VT_OFF 9175040u   // bf16 V^T proj [16][64][2048]  (post-stats: scaled by Sinv)
#define SV_OFF 11272192u  // f32 Sinv      [16][2048] (cast region)

__device__ __forceinline__ u16 f2bf(float f) {
  union { float f; unsigned u; } v; v.f = f;
  unsigned r = v.u + 0x7fff + ((v.u >> 16) & 1);   // RNE
  return (u16)(r >> 16);
}
__device__ __forceinline__ float bf2f(u16 u) {
  union { unsigned u; float f; } v; v.u = ((unsigned)u) << 16; return v.f;
}

// ---------------- prep: f32 -> bf16 for Q,K inputs; W -> bf16 transposed ----------------
__global__ __launch_bounds__(256) void prep_kernel(
    const float* __restrict__ queries, const float* __restrict__ keys,
    const float* __restrict__ WQ, const float* __restrict__ WK,
    const float* __restrict__ WV, u16* __restrict__ wsb) {
  int t = threadIdx.x;
  if (blockIdx.x < 2048) {
    size_t c = (size_t)blockIdx.x * 256 + t;        // chunk of 8 elems
    int tens = (int)(c >> 18);                      // 0=queries, 1=keys
    size_t off = (c & 262143u) * 8;
    const float* src = tens ? keys : queries;
    u16* dst = wsb + (tens ? XK_OFF : XQ_OFF) + off;
    float4 a = *(const float4*)(src + off);
    float4 b = *(const float4*)(src + off + 4);
    short8 o;
    o[0] = (short)f2bf(a.x); o[1] = (short)f2bf(a.y);
    o[2] = (short)f2bf(a.z); o[3] = (short)f2bf(a.w);
    o[4] = (short)f2bf(b.x); o[5] = (short)f2bf(b.y);
    o[6] = (short)f2bf(b.z); o[7] = (short)f2bf(b.w);
    *(short8*)dst = o;
  } else {
    // W transpose: chunk c2 -> Wt[z][h][e][d8*8..+7] from W[z][h][d][e]
    long c2 = (long)(blockIdx.x - 2048) * 256 + t;  // 0..98303
    int d8 = (int)(c2 & 63);
    int e  = (int)((c2 >> 6) & 63);
    int h  = (int)((c2 >> 12) & 7);
    int z  = (int)(c2 >> 15);
    const float* W = (z == 0) ? WQ : (z == 1) ? WK : WV;
    const float* src = W + ((size_t)h * DM + (size_t)d8 * 8) * 64 + e;
    short8 o;
#pragma unroll
    for (int i = 0; i < 8; ++i) o[i] = (short)f2bf(src[(size_t)i * 64]);
    *(short8*)(wsb + WT_OFF + (((size_t)z * 8 + h) * 64 + e) * 512 + (size_t)d8 * 8) = o;
  }
}

// ---------------- proj: LDS-free MFMA GEMM; frags direct from global (L1/L2-hot W) ----------------
__global__ __launch_bounds__(256) void proj_kernel(const float* __restrict__ values,
                                                   u16* __restrict__ wsb) {
  int t = threadIdx.x;
  int lane = t & 63, w = t >> 6, quad = lane >> 4, l16 = lane & 15;
  int z = blockIdx.z, bh = blockIdx.y, b = bh >> 3, h = bh & 7;
  int qbase = blockIdx.x * 64;
  int row = qbase + w * 16 + l16;                  // this lane's A row (m = l16)

  const u16* Ab = wsb + ((z == 0) ? XQ_OFF : XK_OFF);
  const u16* Wz = wsb + WT_OFF + ((size_t)(z * 8 + h) * 64) * 512;
  const size_t arow = ((size_t)b * LL + row) * DM;

  f32x4 acc[4];
#pragma unroll
  for (int nt = 0; nt < 4; ++nt) acc[nt] = (f32x4){0.f, 0.f, 0.f, 0.f};

#pragma unroll 4
  for (int kt = 0; kt < 16; ++kt) {
    short8 a;
    if (z < 2) {
      a = *(const short8*)(Ab + arow + kt * 32 + quad * 8);
    } else {
      const float* p = values + arow + kt * 32 + quad * 8;
      float4 x = *(const float4*)p;
      float4 y = *(const float4*)(p + 4);
      a[0] = (short)f2bf(x.x); a[1] = (short)f2bf(x.y);
      a[2] = (short)f2bf(x.z); a[3] = (short)f2bf(x.w);
      a[4] = (short)f2bf(y.x); a[5] = (short)f2bf(y.y);
      a[6] = (short)f2bf(y.z); a[7] = (short)f2bf(y.w);
    }
#pragma unroll
    for (int nt = 0; nt < 4; ++nt) {
      short8 bb = *(const short8*)(Wz + (size_t)(nt * 16 + l16) * 512 + kt * 32 + quad * 8);
      acc[nt] = __builtin_amdgcn_mfma_f32_16x16x32_bf16(a, bb, acc[nt], 0, 0, 0);
    }
  }

  if (z == 0) {
    u16* og = wsb + QB_OFF + ((size_t)bh * LL + qbase) * 64;
#pragma unroll
    for (int nt = 0; nt < 4; ++nt)
#pragma unroll
      for (int r = 0; r < 4; ++r)
        og[(size_t)(w * 16 + quad * 4 + r) * 64 + nt * 16 + l16] = f2bf(acc[nt][r] * SCALE);
  } else if (z == 1) {
    u16* og = wsb + KB_OFF + ((size_t)bh * LL + qbase) * 64;
#pragma unroll
    for (int nt = 0; nt < 4; ++nt)
#pragma unroll
      for (int r = 0; r < 4; ++r)
        og[(size_t)(w * 16 + quad * 4 + r) * 64 + nt * 16 + l16] = f2bf(acc[nt][r]);
  } else {
    u16* og = wsb + VT_OFF + (size_t)bh * 64 * LL;   // Vt[bh][e][l]
#pragma unroll
    for (int nt = 0; nt < 4; ++nt)
#pragma unroll
      for (int r = 0; r < 4; ++r)
        og[(size_t)(nt * 16 + l16) * LL + qbase + w * 16 + quad * 4 + r] = f2bf(acc[nt][r]);
  }
}

// ---------------- stats: Sinv[k] = 1/sum_q exp(K·Q^T); then scale Vt rows by Sinv ----------------
__global__ __launch_bounds__(256) void stats_kernel(u16* __restrict__ wsb,
                                                    float* __restrict__ Sinv) {
  const u16* Qb = wsb + QB_OFF;
  const u16* Kb = wsb + KB_OFF;
  int t = threadIdx.x;
  int lane = t & 63, w = t >> 6, quad = lane >> 4, l16 = lane & 15;
  int bh = blockIdx.y;
  int kbase = blockIdx.x * 64;

  // A = K rows (wave-private), direct from global
  short8 ka0 = *(const short8*)(Kb + ((size_t)bh * LL + kbase + w * 16 + l16) * 64 + quad * 8);
  short8 ka1 = *(const short8*)(Kb + ((size_t)bh * LL + kbase + w * 16 + l16) * 64 + quad * 8 + 32);

  __shared__ __align__(16) u16 Qsh[64 * 72];
  __shared__ float Ss[64];

  int srow = t >> 3, sc8 = t & 7;                  // staging: f8 = t + rep*256
  int srow2 = (t + 256) >> 3;

  const u16* Qg = Qb + (size_t)bh * LL * 64;
  short8 rq0 = *(const short8*)(Qg + (size_t)srow * 64 + sc8 * 8);
  short8 rq1 = *(const short8*)(Qg + (size_t)srow2 * 64 + sc8 * 8);

  float rs[4] = {0.f, 0.f, 0.f, 0.f};
  for (int qt = 0; qt < 32; ++qt) {
    __syncthreads();
    *(short8*)&Qsh[srow * 72 + sc8 * 8] = rq0;
    *(short8*)&Qsh[srow2 * 72 + sc8 * 8] = rq1;
    // prefetch next tile (qt=31 reads in-bounds ws garbage, never used)
    rq0 = *(const short8*)(Qg + (size_t)((qt + 1) * 64 + srow) * 64 + sc8 * 8);
    rq1 = *(const short8*)(Qg + (size_t)((qt + 1) * 64 + srow2) * 64 + sc8 * 8);
    __syncthreads();
#pragma unroll
    for (int nt = 0; nt < 4; ++nt) {
      short8 b0 = *(const short8*)&Qsh[(nt * 16 + l16) * 72 + quad * 8];
      short8 b1 = *(const short8*)&Qsh[(nt * 16 + l16) * 72 + quad * 8 + 32];
      f32x4 y = (f32x4){0.f, 0.f, 0.f, 0.f};
      y = __builtin_amdgcn_mfma_f32_16x16x32_bf16(ka0, b0, y, 0, 0, 0);
      y = __builtin_amdgcn_mfma_f32_16x16x32_bf16(ka1, b1, y, 0, 0, 0);
#pragma unroll
      for (int r = 0; r < 4; ++r) rs[r] += __expf(y[r]);   // Q pre-scaled
    }
  }
#pragma unroll
  for (int r = 0; r < 4; ++r) {
    rs[r] += __shfl_xor(rs[r], 1);
    rs[r] += __shfl_xor(rs[r], 2);
    rs[r] += __shfl_xor(rs[r], 4);
    rs[r] += __shfl_xor(rs[r], 8);
  }
  if (l16 == 0) {
#pragma unroll
    for (int r = 0; r < 4; ++r) {
      float s = 1.0f / rs[r];
      Sinv[(size_t)bh * LL + kbase + w * 16 + quad * 4 + r] = s;
      Ss[w * 16 + quad * 4 + r] = s;
    }
  }
  __syncthreads();
  // scale Vt[bh][e][kbase..kbase+64) by Sinv (fold softmax denom into V)
#pragma unroll
  for (int rep = 0; rep < 2; ++rep) {
    int f8 = t + rep * 256;
    int e = f8 >> 3, c8 = f8 & 7;
    size_t ad = VT_OFF + ((size_t)bh * 64 + e) * LL + kbase + c8 * 8;
    short8 v = *(const short8*)(wsb + ad);
#pragma unroll
    for (int i = 0; i < 8; ++i)
      v[i] = (short)f2bf(bf2f((u16)v[i]) * Ss[c8 * 8 + i]);
    *(short8*)(wsb + ad) = v;
  }
}

// ---------------- attn: out = exp(Q K^T) · V_scaled via Y^T trick (b64 P-writes) ----------------
__global__ __launch_bounds__(256) void attn_kernel(const u16* __restrict__ wsb,
                                                   float* __restrict__ out) {
  const u16* Qb = wsb + QB_OFF;
  const u16* Kb = wsb + KB_OFF;
  const u16* Vt = wsb + VT_OFF;
  int t = threadIdx.x;
  int lane = t & 63, w = t >> 6, quad = lane >> 4, l16 = lane & 15;
  int bh = blockIdx.y, b = bh >> 3, h = bh & 7;
  int qbase = blockIdx.x * 64;

  __shared__ __align__(16) u16 Ksh[64 * 72];   // [k][d]
  __shared__ __align__(16) u16 Vsh[64 * 72];   // [e][k]
  __shared__ __align__(16) u16 Ps[4 * 16 * 72];
  u16* psw = Ps + w * 16 * 72;                 // wave-private P[16 q][64 k]

  // Q fragments: serve as MFMA B-operand for Y^T = K·Q^T (same layout as A)
  short8 qa0 = *(const short8*)(Qb + ((size_t)bh * LL + qbase + w * 16 + l16) * 64 + quad * 8);
  short8 qa1 = *(const short8*)(Qb + ((size_t)bh * LL + qbase + w * 16 + l16) * 64 + quad * 8 + 32);

  int srow = t >> 3, sc8 = t & 7;
  int srow2 = (t + 256) >> 3;
  const u16* Kg = Kb + (size_t)bh * LL * 64;
  const u16* Vg = Vt + (size_t)bh * 64 * LL;

  short8 rk0 = *(const short8*)(Kg + (size_t)srow * 64 + sc8 * 8);
  short8 rk1 = *(const short8*)(Kg + (size_t)srow2 * 64 + sc8 * 8);
  short8 rv0 = *(const short8*)(Vg + (size_t)srow * LL + sc8 * 8);
  short8 rv1 = *(const short8*)(Vg + (size_t)srow2 * LL + sc8 * 8);

  f32x4 oacc[4];
#pragma unroll
  for (int nt = 0; nt < 4; ++nt) oacc[nt] = (f32x4){0.f, 0.f, 0.f, 0.f};

  for (int kt = 0; kt < 32; ++kt) {
    __syncthreads();                 // previous iter's frag reads done
    *(short8*)&Ksh[srow * 72 + sc8 * 8] = rk0;
    *(short8*)&Ksh[srow2 * 72 + sc8 * 8] = rk1;
    *(short8*)&Vsh[srow * 72 + sc8 * 8] = rv0;
    *(short8*)&Vsh[srow2 * 72 + sc8 * 8] = rv1;
    // prefetch next K/V tile (kt=31 loads valid ws garbage, never stored)
    rk0 = *(const short8*)(Kg + (size_t)((kt + 1) * 64 + srow) * 64 + sc8 * 8);
    rk1 = *(const short8*)(Kg + (size_t)((kt + 1) * 64 + srow2) * 64 + sc8 * 8);
    rv0 = *(const short8*)(Vg + (size_t)srow * LL + (kt + 1) * 64 + sc8 * 8);
    rv1 = *(const short8*)(Vg + (size_t)srow2 * LL + (kt + 1) * 64 + sc8 * 8);
    __syncthreads();                 // tile ready

    // Y^T = K·Q^T: lane gets 4 consecutive k for its own q=l16 -> b64 P-write
#pragma unroll
    for (int mt = 0; mt < 4; ++mt) {
      short8 a0 = *(const short8*)&Ksh[(mt * 16 + l16) * 72 + quad * 8];
      short8 a1 = *(const short8*)&Ksh[(mt * 16 + l16) * 72 + quad * 8 + 32];
      f32x4 y = (f32x4){0.f, 0.f, 0.f, 0.f};
      y = __builtin_amdgcn_mfma_f32_16x16x32_bf16(a0, qa0, y, 0, 0, 0);
      y = __builtin_amdgcn_mfma_f32_16x16x32_bf16(a1, qa1, y, 0, 0, 0);
      short4v p;
      p[0] = (short)f2bf(__expf(y[0]));
      p[1] = (short)f2bf(__expf(y[1]));
      p[2] = (short)f2bf(__expf(y[2]));
      p[3] = (short)f2bf(__expf(y[3]));
      *(short4v*)&psw[l16 * 72 + mt * 16 + quad * 4] = p;
    }
    // PV: A = P (wave-private, no barrier), B = V^T
    short8 pa0 = *(const short8*)&psw[l16 * 72 + quad * 8];
    short8 pa1 = *(const short8*)&psw[l16 * 72 + quad * 8 + 32];
#pragma unroll
    for (int nt = 0; nt < 4; ++nt) {
      short8 v0 = *(const short8*)&Vsh[(nt * 16 + l16) * 72 + quad * 8];
      short8 v1 = *(const short8*)&Vsh[(nt * 16 + l16) * 72 + quad * 8 + 32];
      oacc[nt] = __builtin_amdgcn_mfma_f32_16x16x32_bf16(pa0, v0, oacc[nt], 0, 0, 0);
      oacc[nt] = __builtin_amdgcn_mfma_f32_16x16x32_bf16(pa1, v1, oacc[nt], 0, 0, 0);
    }
  }

  float* og = out + ((size_t)b * LL + qbase) * 512 + h * 64;
#pragma unroll
  for (int nt = 0; nt < 4; ++nt)
#pragma unroll
    for (int r = 0; r < 4; ++r)
      og[(size_t)(w * 16 + quad * 4 + r) * 512 + nt * 16 + l16] = oacc[nt][r];
}

extern "C" void kernel_launch(void* const* d_in, const int* in_sizes, int n_in,
                              void* d_out, int out_size, void* d_ws, size_t ws_size,
                              hipStream_t stream) {
  const float* keys    = (const float*)d_in[0];
  const float* queries = (const float*)d_in[1];
  const float* values  = (const float*)d_in[2];
  const float* WQ      = (const float*)d_in[3];
  const float* WK      = (const float*)d_in[4];
  const float* WV      = (const float*)d_in[5];
  float* out = (float*)d_out;
  u16* wsb = (u16*)d_ws;
  float* Sinv = (float*)(wsb + SV_OFF);

  prep_kernel<<<dim3(2048 + 384), 256, 0, stream>>>(queries, keys, WQ, WK, WV, wsb);
  proj_kernel<<<dim3(32, 16, 3), 256, 0, stream>>>(values, wsb);
  stats_kernel<<<dim3(32, 16), 256, 0, stream>>>(wsb, Sinv);
  attn_kernel<<<dim3(32, 16), 256, 0, stream>>>(wsb, out);
}

// Round 5
// 157.327 us; speedup vs baseline: 1.3059x; 1.3059x over previous
//
#include <hip/hip_runtime.h>
#include <hip/hip_bf16.h>

#define LL 2048
#define DM 512
#define SCALE 0.02209708691207961f   // 1/sqrt(2048)

typedef unsigned short u16;
typedef __attribute__((ext_vector_type(8))) short short8;    // 8 bf16 (4 VGPRs)
typedef __attribute__((ext_vector_type(4))) short short4v;   // 4 bf16 (b64)
typedef __attribute__((ext_vector_type(4))) float f32x4;     // MFMA C/D

// ws layout (u16 element offsets), total 22.68 MB (same as proven R3 budget):
//  XAQ: bf16 queries, A-frag order [2][128 row16][16 kt][64 lane][8]
//  XAK: bf16 keys, same order
//  WB : bf16 weights, B-frag order [3][8][16 kt][4 nt][64 lane][8]
//  QB : bf16 Q proj [16][2048][64] (pre-scaled by SCALE)
//  KB : bf16 K proj [16][2048][64]
//  VT : bf16 V^T proj [16][64][2048] (post-stats: scaled by Sinv)
//  SV : f32 Sinv [16][2048]
#define XAQ_OFF 0u
#define XAK_OFF 2097152u
#define WB_OFF  4194304u
#define QB_OFF  4980736u
#define KB_OFF  7077888u
#define VT_OFF  9175040u
#define SV_OFF  11272192u

__device__ __forceinline__ u16 f2bf(float f) {
  union { float f; unsigned u; } v; v.f = f;
  unsigned r = v.u + 0x7fff + ((v.u >> 16) & 1);   // RNE
  return (u16)(r >> 16);
}
__device__ __forceinline__ float bf2f(u16 u) {
  union { unsigned u; float f; } v; v.u = ((unsigned)u) << 16; return v.f;
}

// ---------------- prep: Q,K -> bf16 in A-frag order; W -> bf16 in B-frag order ----------------
__global__ __launch_bounds__(256) void prep_kernel(
    const float* __restrict__ queries, const float* __restrict__ keys,
    const float* __restrict__ WQ, const float* __restrict__ WK,
    const float* __restrict__ WV, u16* __restrict__ wsb) {
  int t = threadIdx.x;
  if (blockIdx.x < 2048) {
    // X swizzle: chunk -> 8 consecutive d of one row
    size_t c = (size_t)blockIdx.x * 256 + t;        // 0..524287
    int tens = (int)(c >> 18);                      // 0=queries, 1=keys
    size_t off = (c & 262143u) * 8;                 // elem offset in [2][2048][512]
    int b  = (int)(off >> 20);
    int l  = (int)((off >> 9) & 2047);
    int d8 = (int)((off & 511) >> 3);
    int kt = d8 >> 2, quad = d8 & 3;
    const float* src = (tens ? keys : queries) + off;
    float4 a = *(const float4*)(src);
    float4 bb = *(const float4*)(src + 4);
    short8 o;
    o[0] = (short)f2bf(a.x); o[1] = (short)f2bf(a.y);
    o[2] = (short)f2bf(a.z); o[3] = (short)f2bf(a.w);
    o[4] = (short)f2bf(bb.x); o[5] = (short)f2bf(bb.y);
    o[6] = (short)f2bf(bb.z); o[7] = (short)f2bf(bb.w);
    size_t dst = (tens ? XAK_OFF : XAQ_OFF) +
        ((((size_t)b * 128 + (l >> 4)) * 16 + kt) * 64 + (quad * 16 + (l & 15))) * 8;
    *(short8*)(wsb + dst) = o;
  } else {
    // W swizzle into B-frag order: thread = (z,h,kt,nt,lane)
    int c2 = (blockIdx.x - 2048) * 256 + t;         // 0..98303
    int lane = c2 & 63;
    int nt = (c2 >> 6) & 3;
    int kt = (c2 >> 8) & 15;
    int h  = (c2 >> 12) & 7;
    int z  = c2 >> 15;
    int quad = lane >> 4, l16 = lane & 15;
    const float* W = (z == 0) ? WQ : (z == 1) ? WK : WV;
    const float* src = W + ((size_t)h * DM + kt * 32 + quad * 8) * 64 + nt * 16 + l16;
    short8 o;
#pragma unroll
    for (int j = 0; j < 8; ++j) o[j] = (short)f2bf(src[(size_t)j * 64]);
    *(short8*)(wsb + WB_OFF + (size_t)c2 * 8) = o;
  }
}

// ---------------- proj: MFMA GEMM, all fragment loads coalesced ----------------
__global__ __launch_bounds__(256) void proj_kernel(const float* __restrict__ values,
                                                   u16* __restrict__ wsb) {
  int t = threadIdx.x;
  int lane = t & 63, w = t >> 6, quad = lane >> 4, l16 = lane & 15;
  int z = blockIdx.z, bh = blockIdx.y, b = bh >> 3, h = bh & 7;
  int qbase = blockIdx.x * 64;

  const u16* Bw = wsb + WB_OFF + ((size_t)(z * 8 + h) * 16) * 4 * 64 * 8;

  __shared__ __align__(16) short As[64 * 40];      // used by z==2 only

  f32x4 acc[4];
#pragma unroll
  for (int nt = 0; nt < 4; ++nt) acc[nt] = (f32x4){0.f, 0.f, 0.f, 0.f};

  if (z < 2) {
    const u16* Ab = wsb + ((z == 0) ? XAQ_OFF : XAK_OFF) +
        (((size_t)b * 128 + (qbase >> 4) + w) * 16) * 64 * 8;
#pragma unroll 4
    for (int kt = 0; kt < 16; ++kt) {
      short8 a = *(const short8*)(Ab + ((size_t)kt * 64 + lane) * 8);
#pragma unroll
      for (int nt = 0; nt < 4; ++nt) {
        short8 bb = *(const short8*)(Bw + (((size_t)kt * 4 + nt) * 64 + lane) * 8);
        acc[nt] = __builtin_amdgcn_mfma_f32_16x16x32_bf16(a, bb, acc[nt], 0, 0, 0);
      }
    }
  } else {
    const float* inbase = values + ((size_t)b * LL + qbase) * DM;
    for (int kt = 0; kt < 16; ++kt) {
      __syncthreads();
#pragma unroll
      for (int rep = 0; rep < 2; ++rep) {
        int f4 = t + rep * 256;                    // 0..511 float4s (64 rows x 8)
        int row = f4 >> 3, c4 = f4 & 7;
        float4 v = *(const float4*)(inbase + (size_t)row * DM + kt * 32 + c4 * 4);
        short* dst = &As[row * 40 + c4 * 4];
        dst[0] = (short)f2bf(v.x); dst[1] = (short)f2bf(v.y);
        dst[2] = (short)f2bf(v.z); dst[3] = (short)f2bf(v.w);
      }
      __syncthreads();
      short8 a = *(const short8*)&As[(w * 16 + l16) * 40 + quad * 8];
#pragma unroll
      for (int nt = 0; nt < 4; ++nt) {
        short8 bb = *(const short8*)(Bw + (((size_t)kt * 4 + nt) * 64 + lane) * 8);
        acc[nt] = __builtin_amdgcn_mfma_f32_16x16x32_bf16(a, bb, acc[nt], 0, 0, 0);
      }
    }
  }

  // C/D: col = l16, row = quad*4 + r (within wave's 16-row tile)
  if (z == 0) {
    u16* og = wsb + QB_OFF + ((size_t)bh * LL + qbase) * 64;
#pragma unroll
    for (int nt = 0; nt < 4; ++nt)
#pragma unroll
      for (int r = 0; r < 4; ++r)
        og[(size_t)(w * 16 + quad * 4 + r) * 64 + nt * 16 + l16] = f2bf(acc[nt][r] * SCALE);
  } else if (z == 1) {
    u16* og = wsb + KB_OFF + ((size_t)bh * LL + qbase) * 64;
#pragma unroll
    for (int nt = 0; nt < 4; ++nt)
#pragma unroll
      for (int r = 0; r < 4; ++r)
        og[(size_t)(w * 16 + quad * 4 + r) * 64 + nt * 16 + l16] = f2bf(acc[nt][r]);
  } else {
    u16* og = wsb + VT_OFF + (size_t)bh * 64 * LL;   // Vt[bh][e][l]
#pragma unroll
    for (int nt = 0; nt < 4; ++nt)
#pragma unroll
      for (int r = 0; r < 4; ++r)
        og[(size_t)(nt * 16 + l16) * LL + qbase + w * 16 + quad * 4 + r] = f2bf(acc[nt][r]);
  }
}

// ---------------- stats: Sinv[k] = 1/sum_q exp(K·Q^T); then scale Vt rows by Sinv ----------------
__global__ __launch_bounds__(256) void stats_kernel(u16* __restrict__ wsb,
                                                    float* __restrict__ Sinv) {
  const u16* Qb = wsb + QB_OFF;
  const u16* Kb = wsb + KB_OFF;
  int t = threadIdx.x;
  int lane = t & 63, w = t >> 6, quad = lane >> 4, l16 = lane & 15;
  int bh = blockIdx.y;
  int kbase = blockIdx.x * 64;

  // A = K rows (wave-private), direct from global (one-time gather)
  short8 ka0 = *(const short8*)(Kb + ((size_t)bh * LL + kbase + w * 16 + l16) * 64 + quad * 8);
  short8 ka1 = *(const short8*)(Kb + ((size_t)bh * LL + kbase + w * 16 + l16) * 64 + quad * 8 + 32);

  __shared__ __align__(16) u16 Qsh[64 * 72];
  __shared__ float Ss[64];

  int srow = t >> 3, sc8 = t & 7;
  int srow2 = (t + 256) >> 3;

  const u16* Qg = Qb + (size_t)bh * LL * 64;
  short8 rq0 = *(const short8*)(Qg + (size_t)srow * 64 + sc8 * 8);
  short8 rq1 = *(const short8*)(Qg + (size_t)srow2 * 64 + sc8 * 8);

  float rs[4] = {0.f, 0.f, 0.f, 0.f};
  for (int qt = 0; qt < 32; ++qt) {
    __syncthreads();
    *(short8*)&Qsh[srow * 72 + sc8 * 8] = rq0;
    *(short8*)&Qsh[srow2 * 72 + sc8 * 8] = rq1;
    // prefetch next tile (qt=31 reads in-bounds ws garbage, never used)
    rq0 = *(const short8*)(Qg + (size_t)((qt + 1) * 64 + srow) * 64 + sc8 * 8);
    rq1 = *(const short8*)(Qg + (size_t)((qt + 1) * 64 + srow2) * 64 + sc8 * 8);
    __syncthreads();
#pragma unroll
    for (int nt = 0; nt < 4; ++nt) {
      short8 b0 = *(const short8*)&Qsh[(nt * 16 + l16) * 72 + quad * 8];
      short8 b1 = *(const short8*)&Qsh[(nt * 16 + l16) * 72 + quad * 8 + 32];
      f32x4 y = (f32x4){0.f, 0.f, 0.f, 0.f};
      y = __builtin_amdgcn_mfma_f32_16x16x32_bf16(ka0, b0, y, 0, 0, 0);
      y = __builtin_amdgcn_mfma_f32_16x16x32_bf16(ka1, b1, y, 0, 0, 0);
#pragma unroll
      for (int r = 0; r < 4; ++r) rs[r] += __expf(y[r]);   // Q pre-scaled
    }
  }
#pragma unroll
  for (int r = 0; r < 4; ++r) {
    rs[r] += __shfl_xor(rs[r], 1);
    rs[r] += __shfl_xor(rs[r], 2);
    rs[r] += __shfl_xor(rs[r], 4);
    rs[r] += __shfl_xor(rs[r], 8);
  }
  if (l16 == 0) {
#pragma unroll
    for (int r = 0; r < 4; ++r) {
      float s = 1.0f / rs[r];
      Sinv[(size_t)bh * LL + kbase + w * 16 + quad * 4 + r] = s;
      Ss[w * 16 + quad * 4 + r] = s;
    }
  }
  __syncthreads();
  // fold softmax denom into V: scale Vt[bh][e][kbase..kbase+64)
#pragma unroll
  for (int rep = 0; rep < 2; ++rep) {
    int f8 = t + rep * 256;
    int e = f8 >> 3, c8 = f8 & 7;
    size_t ad = VT_OFF + ((size_t)bh * 64 + e) * LL + kbase + c8 * 8;
    short8 v = *(const short8*)(wsb + ad);
#pragma unroll
    for (int i = 0; i < 8; ++i)
      v[i] = (short)f2bf(bf2f((u16)v[i]) * Ss[c8 * 8 + i]);
    *(short8*)(wsb + ad) = v;
  }
}

// ---------------- attn: out = exp(Q K^T) · V_scaled via Y^T trick (b64 P-writes) ----------------
__global__ __launch_bounds__(256) void attn_kernel(const u16* __restrict__ wsb,
                                                   float* __restrict__ out) {
  const u16* Qb = wsb + QB_OFF;
  const u16* Kb = wsb + KB_OFF;
  const u16* Vt = wsb + VT_OFF;
  int t = threadIdx.x;
  int lane = t & 63, w = t >> 6, quad = lane >> 4, l16 = lane & 15;
  int bh = blockIdx.y, b = bh >> 3, h = bh & 7;
  int qbase = blockIdx.x * 64;

  __shared__ __align__(16) u16 Ksh[64 * 72];   // [k][d]
  __shared__ __align__(16) u16 Vsh[64 * 72];   // [e][k]
  __shared__ __align__(16) u16 Ps[4 * 16 * 72];
  u16* psw = Ps + w * 16 * 72;                 // wave-private P[16 q][64 k]

  // Q fragments (MFMA B-operand for Y^T = K·Q^T)
  short8 qa0 = *(const short8*)(Qb + ((size_t)bh * LL + qbase + w * 16 + l16) * 64 + quad * 8);
  short8 qa1 = *(const short8*)(Qb + ((size_t)bh * LL + qbase + w * 16 + l16) * 64 + quad * 8 + 32);

  int srow = t >> 3, sc8 = t & 7;
  int srow2 = (t + 256) >> 3;
  const u16* Kg = Kb + (size_t)bh * LL * 64;
  const u16* Vg = Vt + (size_t)bh * 64 * LL;

  short8 rk0 = *(const short8*)(Kg + (size_t)srow * 64 + sc8 * 8);
  short8 rk1 = *(const short8*)(Kg + (size_t)srow2 * 64 + sc8 * 8);
  short8 rv0 = *(const short8*)(Vg + (size_t)srow * LL + sc8 * 8);
  short8 rv1 = *(const short8*)(Vg + (size_t)srow2 * LL + sc8 * 8);

  f32x4 oacc[4];
#pragma unroll
  for (int nt = 0; nt < 4; ++nt) oacc[nt] = (f32x4){0.f, 0.f, 0.f, 0.f};

  for (int kt = 0; kt < 32; ++kt) {
    __syncthreads();
    *(short8*)&Ksh[srow * 72 + sc8 * 8] = rk0;
    *(short8*)&Ksh[srow2 * 72 + sc8 * 8] = rk1;
    *(short8*)&Vsh[srow * 72 + sc8 * 8] = rv0;
    *(short8*)&Vsh[srow2 * 72 + sc8 * 8] = rv1;
    rk0 = *(const short8*)(Kg + (size_t)((kt + 1) * 64 + srow) * 64 + sc8 * 8);
    rk1 = *(const short8*)(Kg + (size_t)((kt + 1) * 64 + srow2) * 64 + sc8 * 8);
    rv0 = *(const short8*)(Vg + (size_t)srow * LL + (kt + 1) * 64 + sc8 * 8);
    rv1 = *(const short8*)(Vg + (size_t)srow2 * LL + (kt + 1) * 64 + sc8 * 8);
    __syncthreads();

    // Y^T = K·Q^T: lane gets 4 consecutive k for its own q=l16 -> b64 P-write
#pragma unroll
    for (int mt = 0; mt < 4; ++mt) {
      short8 a0 = *(const short8*)&Ksh[(mt * 16 + l16) * 72 + quad * 8];
      short8 a1 = *(const short8*)&Ksh[(mt * 16 + l16) * 72 + quad * 8 + 32];
      f32x4 y = (f32x4){0.f, 0.f, 0.f, 0.f};
      y = __builtin_amdgcn_mfma_f32_16x16x32_bf16(a0, qa0, y, 0, 0, 0);
      y = __builtin_amdgcn_mfma_f32_16x16x32_bf16(a1, qa1, y, 0, 0, 0);
      short4v p;
      p[0] = (short)f2bf(__expf(y[0]));
      p[1] = (short)f2bf(__expf(y[1]));
      p[2] = (short)f2bf(__expf(y[2]));
      p[3] = (short)f2bf(__expf(y[3]));
      *(short4v*)&psw[l16 * 72 + mt * 16 + quad * 4] = p;
    }
    // PV: A = P (wave-private, no barrier), B = V^T
    short8 pa0 = *(const short8*)&psw[l16 * 72 + quad * 8];
    short8 pa1 = *(const short8*)&psw[l16 * 72 + quad * 8 + 32];
#pragma unroll
    for (int nt = 0; nt < 4; ++nt) {
      short8 v0 = *(const short8*)&Vsh[(nt * 16 + l16) * 72 + quad * 8];
      short8 v1 = *(const short8*)&Vsh[(nt * 16 + l16) * 72 + quad * 8 + 32];
      oacc[nt] = __builtin_amdgcn_mfma_f32_16x16x32_bf16(pa0, v0, oacc[nt], 0, 0, 0);
      oacc[nt] = __builtin_amdgcn_mfma_f32_16x16x32_bf16(pa1, v1, oacc[nt], 0, 0, 0);
    }
  }

  float* og = out + ((size_t)b * LL + qbase) * 512 + h * 64;
#pragma unroll
  for (int nt = 0; nt < 4; ++nt)
#pragma unroll
    for (int r = 0; r < 4; ++r)
      og[(size_t)(w * 16 + quad * 4 + r) * 512 + nt * 16 + l16] = oacc[nt][r];
}

extern "C" void kernel_launch(void* const* d_in, const int* in_sizes, int n_in,
                              void* d_out, int out_size, void* d_ws, size_t ws_size,
                              hipStream_t stream) {
  const float* keys    = (const float*)d_in[0];
  const float* queries = (const float*)d_in[1];
  const float* values  = (const float*)d_in[2];
  const float* WQ      = (const float*)d_in[3];
  const float* WK      = (const float*)d_in[4];
  const float* WV      = (const float*)d_in[5];
  float* out = (float*)d_out;
  u16* wsb = (u16*)d_ws;
  float* Sinv = (float*)(wsb + SV_OFF);

  prep_kernel<<<dim3(2048 + 384), 256, 0, stream>>>(queries, keys, WQ, WK, WV, wsb);
  proj_kernel<<<dim3(32, 16, 3), 256, 0, stream>>>(values, wsb);
  stats_kernel<<<dim3(32, 16), 256, 0, stream>>>(wsb, Sinv);
  attn_kernel<<<dim3(32, 16), 256, 0, stream>>>(wsb, out);
}

// Round 6
// 147.524 us; speedup vs baseline: 1.3927x; 1.0664x over previous
//
#include <hip/hip_runtime.h>
#include <hip/hip_bf16.h>

#define LL 2048
#define DM 512
#define SCALE 0.02209708691207961f   // 1/sqrt(2048)

typedef unsigned short u16;
typedef __attribute__((ext_vector_type(8))) short short8;    // 8 bf16 (4 VGPRs)
typedef __attribute__((ext_vector_type(4))) short short4v;   // 4 bf16 (2 VGPRs)
typedef __attribute__((ext_vector_type(4))) float f32x4;     // MFMA C/D

// ws layout (u16 element offsets); ws is 256 MiB (measured via harness poison), use 26.7 MB:
//  XAQ/XAK: bf16 inputs in proj-A-frag order (unchanged from R4)
//  WB     : bf16 weights in B-frag order (unchanged)
//  QA/KA  : bf16 Q,K projections in MFMA frag order:
//           FRAG(bh,t64,w,c,lane,j) -> row t64*64+w*16+(lane&15), d=c*32+(lane>>4)*8+j
//           (Q pre-scaled by SCALE)
//  VT     : bf16 V^T proj [16][64 e][2048 k] (raw, pre-Sinv)
//  VB     : bf16 V in PV-B-frag order, scaled by Sinv:
//           VB(bh,kt,w,et,lane,j) -> V[kt*64+w*16+(lane>>4)*4+j][et*16+(lane&15)]
#define XAQ_OFF 0u
#define XAK_OFF 2097152u
#define WB_OFF  4194304u
#define QA_OFF  4980736u
#define KA_OFF  7077888u
#define VT_OFF  9175040u
#define VB_OFF  11272192u

__device__ __forceinline__ u16 f2bf(float f) {
  union { float f; unsigned u; } v; v.f = f;
  unsigned r = v.u + 0x7fff + ((v.u >> 16) & 1);   // RNE
  return (u16)(r >> 16);
}
__device__ __forceinline__ float bf2f(u16 u) {
  union { unsigned u; float f; } v; v.u = ((unsigned)u) << 16; return v.f;
}
__device__ __forceinline__ size_t frag_idx(int bh, int t64, int w, int c, int lane) {
  return ((((size_t)(bh * 32 + t64) * 4 + w) * 2 + c) * 64 + lane) * 8;
}
__device__ __forceinline__ size_t vb_idx(int bh, int kt, int w, int et, int lane) {
  return ((((size_t)(bh * 32 + kt) * 4 + w) * 4 + et) * 64 + lane) * 4;
}

// ---------------- prep: Q,K -> bf16 in A-frag order; W -> bf16 in B-frag order ----------------
__global__ __launch_bounds__(256) void prep_kernel(
    const float* __restrict__ queries, const float* __restrict__ keys,
    const float* __restrict__ WQ, const float* __restrict__ WK,
    const float* __restrict__ WV, u16* __restrict__ wsb) {
  int t = threadIdx.x;
  if (blockIdx.x < 2048) {
    size_t c = (size_t)blockIdx.x * 256 + t;
    int tens = (int)(c >> 18);                      // 0=queries, 1=keys
    size_t off = (c & 262143u) * 8;
    int b  = (int)(off >> 20);
    int l  = (int)((off >> 9) & 2047);
    int d8 = (int)((off & 511) >> 3);
    int kt = d8 >> 2, quad = d8 & 3;
    const float* src = (tens ? keys : queries) + off;
    float4 a = *(const float4*)(src);
    float4 bb = *(const float4*)(src + 4);
    short8 o;
    o[0] = (short)f2bf(a.x); o[1] = (short)f2bf(a.y);
    o[2] = (short)f2bf(a.z); o[3] = (short)f2bf(a.w);
    o[4] = (short)f2bf(bb.x); o[5] = (short)f2bf(bb.y);
    o[6] = (short)f2bf(bb.z); o[7] = (short)f2bf(bb.w);
    size_t dst = (tens ? XAK_OFF : XAQ_OFF) +
        ((((size_t)b * 128 + (l >> 4)) * 16 + kt) * 64 + (quad * 16 + (l & 15))) * 8;
    *(short8*)(wsb + dst) = o;
  } else {
    int c2 = (blockIdx.x - 2048) * 256 + t;
    int lane = c2 & 63;
    int nt = (c2 >> 6) & 3;
    int kt = (c2 >> 8) & 15;
    int h  = (c2 >> 12) & 7;
    int z  = c2 >> 15;
    int quad = lane >> 4, l16 = lane & 15;
    const float* W = (z == 0) ? WQ : (z == 1) ? WK : WV;
    const float* src = W + ((size_t)h * DM + kt * 32 + quad * 8) * 64 + nt * 16 + l16;
    short8 o;
#pragma unroll
    for (int j = 0; j < 8; ++j) o[j] = (short)f2bf(src[(size_t)j * 64]);
    *(short8*)(wsb + WB_OFF + (size_t)c2 * 8) = o;
  }
}

// ---------------- proj: MFMA GEMM; Q/K epilogue writes frag-order QA/KA ----------------
__global__ __launch_bounds__(256) void proj_kernel(const float* __restrict__ values,
                                                   u16* __restrict__ wsb) {
  int t = threadIdx.x;
  int lane = t & 63, w = t >> 6, quad = lane >> 4, l16 = lane & 15;
  int z = blockIdx.z, bh = blockIdx.y, b = bh >> 3, h = bh & 7;
  int QT = blockIdx.x, qbase = QT * 64;

  const u16* Bw = wsb + WB_OFF + ((size_t)(z * 8 + h) * 16) * 4 * 64 * 8;
  __shared__ __align__(16) short As[64 * 40];      // z==2 only

  f32x4 acc[4];
#pragma unroll
  for (int nt = 0; nt < 4; ++nt) acc[nt] = (f32x4){0.f, 0.f, 0.f, 0.f};

  if (z < 2) {
    const u16* Ab = wsb + ((z == 0) ? XAQ_OFF : XAK_OFF) +
        (((size_t)b * 128 + (qbase >> 4) + w) * 16) * 64 * 8;
#pragma unroll 4
    for (int kt = 0; kt < 16; ++kt) {
      short8 a = *(const short8*)(Ab + ((size_t)kt * 64 + lane) * 8);
#pragma unroll
      for (int nt = 0; nt < 4; ++nt) {
        short8 bb = *(const short8*)(Bw + (((size_t)kt * 4 + nt) * 64 + lane) * 8);
        acc[nt] = __builtin_amdgcn_mfma_f32_16x16x32_bf16(a, bb, acc[nt], 0, 0, 0);
      }
    }
  } else {
    const float* inbase = values + ((size_t)b * LL + qbase) * DM;
    for (int kt = 0; kt < 16; ++kt) {
      __syncthreads();
#pragma unroll
      for (int rep = 0; rep < 2; ++rep) {
        int f4 = t + rep * 256;
        int row = f4 >> 3, c4 = f4 & 7;
        float4 v = *(const float4*)(inbase + (size_t)row * DM + kt * 32 + c4 * 4);
        short* dst = &As[row * 40 + c4 * 4];
        dst[0] = (short)f2bf(v.x); dst[1] = (short)f2bf(v.y);
        dst[2] = (short)f2bf(v.z); dst[3] = (short)f2bf(v.w);
      }
      __syncthreads();
      short8 a = *(const short8*)&As[(w * 16 + l16) * 40 + quad * 8];
#pragma unroll
      for (int nt = 0; nt < 4; ++nt) {
        short8 bb = *(const short8*)(Bw + (((size_t)kt * 4 + nt) * 64 + lane) * 8);
        acc[nt] = __builtin_amdgcn_mfma_f32_16x16x32_bf16(a, bb, acc[nt], 0, 0, 0);
      }
    }
  }

  if (z < 2) {
    // write frag-order: row = qbase + w*16 + quad*4 + r, d = nt*16 + l16
    u16* base = wsb + ((z == 0) ? QA_OFF : KA_OFF);
    float sc = (z == 0) ? SCALE : 1.0f;
#pragma unroll
    for (int nt = 0; nt < 4; ++nt) {
      int c = nt >> 1;
      int quadp = (nt & 1) * 2 + (l16 >> 3);
      int j = l16 & 7;
#pragma unroll
      for (int r = 0; r < 4; ++r) {
        int lanep = quadp * 16 + quad * 4 + r;
        base[frag_idx(bh, QT, w, c, lanep) + j] = f2bf(acc[nt][r] * sc);
      }
    }
  } else {
    u16* og = wsb + VT_OFF + (size_t)bh * 64 * LL;   // Vt[bh][e][l]
#pragma unroll
    for (int nt = 0; nt < 4; ++nt)
#pragma unroll
      for (int r = 0; r < 4; ++r)
        og[(size_t)(nt * 16 + l16) * LL + qbase + w * 16 + quad * 4 + r] = f2bf(acc[nt][r]);
  }
}

// ---------------- stats: Sinv[k] = 1/sum_q exp(K·Q^T); scale Vt -> frag-order VB ----------------
__global__ __launch_bounds__(256) void stats_kernel(u16* __restrict__ wsb) {
  int t = threadIdx.x;
  int lane = t & 63, w = t >> 6, quad = lane >> 4, l16 = lane & 15;
  int bh = blockIdx.y;
  int KT = blockIdx.x;

  // K-tile A-frags for all 4 mt, loop-invariant (coalesced loads)
  short8 ka[4][2];
#pragma unroll
  for (int mt = 0; mt < 4; ++mt)
#pragma unroll
    for (int c = 0; c < 2; ++c)
      ka[mt][c] = *(const short8*)(wsb + KA_OFF + frag_idx(bh, KT, mt, c, lane));

  float rs[4][4];
#pragma unroll
  for (int mt = 0; mt < 4; ++mt)
#pragma unroll
    for (int r = 0; r < 4; ++r) rs[mt][r] = 0.f;

  for (int qt = 0; qt < 32; ++qt) {
    short8 qb0 = *(const short8*)(wsb + QA_OFF + frag_idx(bh, qt, w, 0, lane));
    short8 qb1 = *(const short8*)(wsb + QA_OFF + frag_idx(bh, qt, w, 1, lane));
#pragma unroll
    for (int mt = 0; mt < 4; ++mt) {
      f32x4 y = (f32x4){0.f, 0.f, 0.f, 0.f};
      y = __builtin_amdgcn_mfma_f32_16x16x32_bf16(ka[mt][0], qb0, y, 0, 0, 0);
      y = __builtin_amdgcn_mfma_f32_16x16x32_bf16(ka[mt][1], qb1, y, 0, 0, 0);
#pragma unroll
      for (int r = 0; r < 4; ++r) rs[mt][r] += __expf(y[r]);
    }
  }
  // sum over the 16 q-lanes (l16 bits)
#pragma unroll
  for (int mt = 0; mt < 4; ++mt)
#pragma unroll
    for (int r = 0; r < 4; ++r) {
      rs[mt][r] += __shfl_xor(rs[mt][r], 1);
      rs[mt][r] += __shfl_xor(rs[mt][r], 2);
      rs[mt][r] += __shfl_xor(rs[mt][r], 4);
      rs[mt][r] += __shfl_xor(rs[mt][r], 8);
    }

  __shared__ float Sred[4][64];
  __shared__ float Ss[64];
  if (l16 == 0) {
#pragma unroll
    for (int mt = 0; mt < 4; ++mt)
#pragma unroll
      for (int r = 0; r < 4; ++r)
        Sred[w][mt * 16 + quad * 4 + r] = rs[mt][r];
  }
  __syncthreads();
  if (t < 64) Ss[t] = 1.0f / (Sred[0][t] + Sred[1][t] + Sred[2][t] + Sred[3][t]);
  __syncthreads();

  // Vt * Sinv -> VB (PV B-frag order)
#pragma unroll
  for (int rep = 0; rep < 2; ++rep) {
    int f8 = t + rep * 256;
    int e = f8 >> 3, c8 = f8 & 7;
    const u16* src = wsb + VT_OFF + ((size_t)bh * 64 + e) * LL + KT * 64 + c8 * 8;
    short8 v = *(const short8*)src;
    float sv[8];
#pragma unroll
    for (int i = 0; i < 8; ++i) sv[i] = bf2f((u16)v[i]) * Ss[c8 * 8 + i];
    int wv = c8 >> 1, et = e >> 4;
#pragma unroll
    for (int g = 0; g < 2; ++g) {
      short4v o;
#pragma unroll
      for (int j = 0; j < 4; ++j) o[j] = (short)f2bf(sv[g * 4 + j]);
      int lanep = ((c8 & 1) * 2 + g) * 16 + (e & 15);
      *(short4v*)(wsb + VB_OFF + vb_idx(bh, KT, wv, et, lanep)) = o;
    }
  }
}

// ---------------- attn: barrier-free k-partitioned stream; P stays in registers ----------------
__global__ __launch_bounds__(256, 2) void attn_kernel(const u16* __restrict__ wsb,
                                                      float* __restrict__ out) {
  int t = threadIdx.x;
  int lane = t & 63, w = t >> 6, quad = lane >> 4, l16 = lane & 15;
  int bh = blockIdx.y, b = bh >> 3, h = bh & 7;
  int QT = blockIdx.x, qbase = QT * 64;

  // Q B-frags for the block's 64 q (loop-invariant)
  short8 qf[4][2];
#pragma unroll
  for (int nt = 0; nt < 4; ++nt)
#pragma unroll
    for (int c = 0; c < 2; ++c)
      qf[nt][c] = *(const short8*)(wsb + QA_OFF + frag_idx(bh, QT, nt, c, lane));

  f32x4 oacc[4][4];
#pragma unroll
  for (int nt = 0; nt < 4; ++nt)
#pragma unroll
    for (int et = 0; et < 4; ++et) oacc[nt][et] = (f32x4){0.f, 0.f, 0.f, 0.f};

  for (int kt = 0; kt < 32; ++kt) {
    // wave-private K rows (16 of the 64-k tile) + matching V chunk — disjoint, coalesced
    short8 ka0 = *(const short8*)(wsb + KA_OFF + frag_idx(bh, kt, w, 0, lane));
    short8 ka1 = *(const short8*)(wsb + KA_OFF + frag_idx(bh, kt, w, 1, lane));
    short4v vb[4];
#pragma unroll
    for (int et = 0; et < 4; ++et)
      vb[et] = *(const short4v*)(wsb + VB_OFF + vb_idx(bh, kt, w, et, lane));

#pragma unroll
    for (int nt = 0; nt < 4; ++nt) {
      f32x4 y = (f32x4){0.f, 0.f, 0.f, 0.f};
      y = __builtin_amdgcn_mfma_f32_16x16x32_bf16(ka0, qf[nt][0], y, 0, 0, 0);
      y = __builtin_amdgcn_mfma_f32_16x16x32_bf16(ka1, qf[nt][1], y, 0, 0, 0);
      // lane holds P[q=nt*16+l16][k=quad*4+r] == A-frag of 16x16x16 MFMA: no LDS roundtrip
      short4v pa;
#pragma unroll
      for (int r = 0; r < 4; ++r) pa[r] = (short)f2bf(__expf(y[r]));
#pragma unroll
      for (int et = 0; et < 4; ++et)
        oacc[nt][et] = __builtin_amdgcn_mfma_f32_16x16x16bf16_1k(pa, vb[et], oacc[nt][et], 0, 0, 0);
    }
  }

  // cross-wave k-reduction (the only LDS + barrier in this kernel)
  __shared__ float red[4][64][68];
#pragma unroll
  for (int nt = 0; nt < 4; ++nt)
#pragma unroll
    for (int et = 0; et < 4; ++et)
#pragma unroll
      for (int r = 0; r < 4; ++r)
        red[w][nt * 16 + quad * 4 + r][et * 16 + l16] = oacc[nt][et][r];
  __syncthreads();
  float* og = out + ((size_t)b * LL + qbase + w * 16) * 512 + h * 64;
#pragma unroll
  for (int i = 0; i < 16; ++i) {
    float s = red[0][w * 16 + i][lane] + red[1][w * 16 + i][lane] +
              red[2][w * 16 + i][lane] + red[3][w * 16 + i][lane];
    og[(size_t)i * 512 + lane] = s;
  }
}

extern "C" void kernel_launch(void* const* d_in, const int* in_sizes, int n_in,
                              void* d_out, int out_size, void* d_ws, size_t ws_size,
                              hipStream_t stream) {
  const float* keys    = (const float*)d_in[0];
  const float* queries = (const float*)d_in[1];
  const float* values  = (const float*)d_in[2];
  const float* WQ      = (const float*)d_in[3];
  const float* WK      = (const float*)d_in[4];
  const float* WV      = (const float*)d_in[5];
  float* out = (float*)d_out;
  u16* wsb = (u16*)d_ws;

  prep_kernel<<<dim3(2048 + 384), 256, 0, stream>>>(queries, keys, WQ, WK, WV, wsb);
  proj_kernel<<<dim3(32, 16, 3), 256, 0, stream>>>(values, wsb);
  stats_kernel<<<dim3(32, 16), 256, 0, stream>>>(wsb);
  attn_kernel<<<dim3(32, 16), 256, 0, stream>>>(wsb, out);
}

// Round 7
// 143.386 us; speedup vs baseline: 1.4329x; 1.0289x over previous
//
#include <hip/hip_runtime.h>
#include <hip/hip_bf16.h>

#define LL 2048
#define DM 512
#define SCALE 0.02209708691207961f   // 1/sqrt(2048)

typedef unsigned short u16;
typedef __attribute__((ext_vector_type(8))) short short8;    // 8 bf16 (4 VGPRs)
typedef __attribute__((ext_vector_type(4))) short short4v;   // 4 bf16 (2 VGPRs)
typedef __attribute__((ext_vector_type(4))) float f32x4;     // MFMA C/D

// ws layout (u16 element offsets), 26.7 MB of the 256 MiB ws:
//  XAQ/XAK/XAV: bf16 inputs in proj-A-frag order [2][128 r16][16 kt][64 lane][8]
//  WB : bf16 weights in B-frag order [3][8][16 kt][4 nt][64 lane][8]
//  QA/KA: bf16 Q,K projections in frag order (Q pre-scaled by SCALE):
//         frag_idx(bh,t64,w,c,lane)+j -> row t64*64+w*16+(lane&15), d=c*32+(lane>>4)*8+j
//  VB : bf16 V in PV-B-frag order (stats scales by Sinv in place):
//       vb_idx(bh,kt,w,et,lane)+j -> V[kt*64+w*16+(lane>>4)*4+j][et*16+(lane&15)]
#define XAQ_OFF 0u
#define XAK_OFF 2097152u
#define XAV_OFF 4194304u
#define WB_OFF  6291456u
#define QA_OFF  7077888u
#define KA_OFF  9175040u
#define VB_OFF  11272192u

__device__ __forceinline__ u16 f2bf(float f) {
  union { float f; unsigned u; } v; v.f = f;
  unsigned r = v.u + 0x7fff + ((v.u >> 16) & 1);   // RNE
  return (u16)(r >> 16);
}
__device__ __forceinline__ float bf2f(u16 u) {
  union { unsigned u; float f; } v; v.u = ((unsigned)u) << 16; return v.f;
}
__device__ __forceinline__ size_t frag_idx(int bh, int t64, int w, int c, int lane) {
  return ((((size_t)(bh * 32 + t64) * 4 + w) * 2 + c) * 64 + lane) * 8;
}
__device__ __forceinline__ size_t vb_idx(int bh, int kt, int w, int et, int lane) {
  return ((((size_t)(bh * 32 + kt) * 4 + w) * 4 + et) * 64 + lane) * 4;
}

// ---------------- prep: X -> frag order via LDS transpose; W -> B-frag order ----------------
__global__ __launch_bounds__(256) void prep_kernel(
    const float* __restrict__ queries, const float* __restrict__ keys,
    const float* __restrict__ values, const float* __restrict__ WQ,
    const float* __restrict__ WK, const float* __restrict__ WV,
    u16* __restrict__ wsb) {
  int t = threadIdx.x;
  int blk = blockIdx.x;
  if (blk < 768) {
    int tens = blk >> 8;                       // 0=Q,1=K,2=V
    int grp  = blk & 255;                      // b*128 + r16
    const float* src = (tens == 0 ? queries : tens == 1 ? keys : values) +
                       (size_t)grp * 16 * 512;
    __shared__ __align__(16) u16 Xs[16][520];
    // stage: coalesced float4 reads, bf16 convert, b64 LDS writes
#pragma unroll
    for (int rep = 0; rep < 8; ++rep) {
      int f4 = t + rep * 256;                  // 0..2047
      int row = f4 >> 7, c4 = f4 & 127;
      float4 v = *(const float4*)(src + (size_t)row * 512 + c4 * 4);
      short4v o;
      o[0] = (short)f2bf(v.x); o[1] = (short)f2bf(v.y);
      o[2] = (short)f2bf(v.z); o[3] = (short)f2bf(v.w);
      *(short4v*)&Xs[row][c4 * 4] = o;
    }
    __syncthreads();
    // drain: frag-order b128 LDS reads, fully-coalesced b128 global writes
    u16* dst = wsb + (tens == 0 ? XAQ_OFF : tens == 1 ? XAK_OFF : XAV_OFF) +
               (size_t)grp * 16 * 64 * 8;
#pragma unroll
    for (int rep = 0; rep < 4; ++rep) {
      int o = t + rep * 256;                   // kt*64 + lane
      int kt = o >> 6, lane = o & 63;
      int quad = lane >> 4, l16 = lane & 15;
      short8 v = *(const short8*)&Xs[l16][kt * 32 + quad * 8];
      *(short8*)(dst + (size_t)o * 8) = v;
    }
  } else {
    int c2 = (blk - 768) * 256 + t;            // 0..98303
    int lane = c2 & 63;
    int nt = (c2 >> 6) & 3;
    int kt = (c2 >> 8) & 15;
    int h  = (c2 >> 12) & 7;
    int z  = c2 >> 15;
    int quad = lane >> 4, l16 = lane & 15;
    const float* W = (z == 0) ? WQ : (z == 1) ? WK : WV;
    const float* src = W + ((size_t)h * DM + kt * 32 + quad * 8) * 64 + nt * 16 + l16;
    short8 o;
#pragma unroll
    for (int j = 0; j < 8; ++j) o[j] = (short)f2bf(src[(size_t)j * 64]);
    *(short8*)(wsb + WB_OFF + (size_t)c2 * 8) = o;
  }
}

// ---------------- proj: barrier-free MFMA GEMM; coalesced frag-order epilogue via LDS ----------------
__global__ __launch_bounds__(256) void proj_kernel(u16* __restrict__ wsb) {
  int t = threadIdx.x;
  int lane = t & 63, w = t >> 6, quad = lane >> 4, l16 = lane & 15;
  int z = blockIdx.z, bh = blockIdx.y, b = bh >> 3, h = bh & 7;
  int QT = blockIdx.x;

  const u16* Bw = wsb + WB_OFF + ((size_t)(z * 8 + h) * 16) * 4 * 64 * 8;
  const u16* Ab = wsb + (z == 0 ? XAQ_OFF : z == 1 ? XAK_OFF : XAV_OFF) +
      (((size_t)b * 128 + QT * 4 + w) * 16) * 64 * 8;

  f32x4 acc[4];
#pragma unroll
  for (int nt = 0; nt < 4; ++nt) acc[nt] = (f32x4){0.f, 0.f, 0.f, 0.f};

#pragma unroll 4
  for (int kt = 0; kt < 16; ++kt) {
    short8 a = *(const short8*)(Ab + ((size_t)kt * 64 + lane) * 8);
#pragma unroll
    for (int nt = 0; nt < 4; ++nt) {
      short8 bb = *(const short8*)(Bw + (((size_t)kt * 4 + nt) * 64 + lane) * 8);
      acc[nt] = __builtin_amdgcn_mfma_f32_16x16x32_bf16(a, bb, acc[nt], 0, 0, 0);
    }
  }

  // epilogue: C-layout -> LDS -> frag-order coalesced global writes
  __shared__ float Cs[64][68];
  float sc = (z == 0) ? SCALE : 1.0f;
#pragma unroll
  for (int nt = 0; nt < 4; ++nt)
#pragma unroll
    for (int r = 0; r < 4; ++r)
      Cs[w * 16 + quad * 4 + r][nt * 16 + l16] = acc[nt][r] * sc;
  __syncthreads();

  if (z < 2) {
    u16* base = wsb + (z == 0 ? QA_OFF : KA_OFF);
#pragma unroll
    for (int c = 0; c < 2; ++c) {
      const float* srcr = &Cs[w * 16 + l16][c * 32 + quad * 8];
      short8 o;
#pragma unroll
      for (int j = 0; j < 8; ++j) o[j] = (short)f2bf(srcr[j]);
      *(short8*)(base + frag_idx(bh, QT, w, c, lane)) = o;
    }
  } else {
#pragma unroll
    for (int et = 0; et < 4; ++et) {
      short4v o;
#pragma unroll
      for (int j = 0; j < 4; ++j)
        o[j] = (short)f2bf(Cs[w * 16 + quad * 4 + j][et * 16 + l16]);
      *(short4v*)(wsb + VB_OFF + vb_idx(bh, QT, w, et, lane)) = o;
    }
  }
}

// ---------------- stats: Sinv over q; scale VB in place ----------------
__global__ __launch_bounds__(256) void stats_kernel(u16* __restrict__ wsb) {
  int t = threadIdx.x;
  int lane = t & 63, w = t >> 6, quad = lane >> 4, l16 = lane & 15;
  int bh = blockIdx.y;
  int KT = blockIdx.x;

  short8 ka[4][2];
#pragma unroll
  for (int mt = 0; mt < 4; ++mt)
#pragma unroll
    for (int c = 0; c < 2; ++c)
      ka[mt][c] = *(const short8*)(wsb + KA_OFF + frag_idx(bh, KT, mt, c, lane));

  float rs[4][4];
#pragma unroll
  for (int mt = 0; mt < 4; ++mt)
#pragma unroll
    for (int r = 0; r < 4; ++r) rs[mt][r] = 0.f;

  for (int qt = 0; qt < 32; ++qt) {
    short8 qb0 = *(const short8*)(wsb + QA_OFF + frag_idx(bh, qt, w, 0, lane));
    short8 qb1 = *(const short8*)(wsb + QA_OFF + frag_idx(bh, qt, w, 1, lane));
#pragma unroll
    for (int mt = 0; mt < 4; ++mt) {
      f32x4 y = (f32x4){0.f, 0.f, 0.f, 0.f};
      y = __builtin_amdgcn_mfma_f32_16x16x32_bf16(ka[mt][0], qb0, y, 0, 0, 0);
      y = __builtin_amdgcn_mfma_f32_16x16x32_bf16(ka[mt][1], qb1, y, 0, 0, 0);
#pragma unroll
      for (int r = 0; r < 4; ++r) rs[mt][r] += __expf(y[r]);
    }
  }
#pragma unroll
  for (int mt = 0; mt < 4; ++mt)
#pragma unroll
    for (int r = 0; r < 4; ++r) {
      rs[mt][r] += __shfl_xor(rs[mt][r], 1);
      rs[mt][r] += __shfl_xor(rs[mt][r], 2);
      rs[mt][r] += __shfl_xor(rs[mt][r], 4);
      rs[mt][r] += __shfl_xor(rs[mt][r], 8);
    }

  __shared__ float Sred[4][64];
  __shared__ float Ss[64];
  if (l16 == 0) {
#pragma unroll
    for (int mt = 0; mt < 4; ++mt)
#pragma unroll
      for (int r = 0; r < 4; ++r)
        Sred[w][mt * 16 + quad * 4 + r] = rs[mt][r];
  }
  __syncthreads();
  if (t < 64) Ss[t] = 1.0f / (Sred[0][t] + Sred[1][t] + Sred[2][t] + Sred[3][t]);
  __syncthreads();

  // scale this k-tile's VB frags in place (coalesced b64 RMW)
#pragma unroll
  for (int et = 0; et < 4; ++et) {
    u16* p = wsb + VB_OFF + vb_idx(bh, KT, w, et, lane);
    short4v v = *(short4v*)p;
#pragma unroll
    for (int j = 0; j < 4; ++j)
      v[j] = (short)f2bf(bf2f((u16)v[j]) * Ss[w * 16 + quad * 4 + j]);
    *(short4v*)p = v;
  }
}

// ---------------- attn: barrier-free k-partitioned stream; P stays in registers ----------------
__global__ __launch_bounds__(256, 2) void attn_kernel(const u16* __restrict__ wsb,
                                                      float* __restrict__ out) {
  int t = threadIdx.x;
  int lane = t & 63, w = t >> 6, quad = lane >> 4, l16 = lane & 15;
  int bh = blockIdx.y, b = bh >> 3, h = bh & 7;
  int QT = blockIdx.x, qbase = QT * 64;

  short8 qf[4][2];
#pragma unroll
  for (int nt = 0; nt < 4; ++nt)
#pragma unroll
    for (int c = 0; c < 2; ++c)
      qf[nt][c] = *(const short8*)(wsb + QA_OFF + frag_idx(bh, QT, nt, c, lane));

  f32x4 oacc[4][4];
#pragma unroll
  for (int nt = 0; nt < 4; ++nt)
#pragma unroll
    for (int et = 0; et < 4; ++et) oacc[nt][et] = (f32x4){0.f, 0.f, 0.f, 0.f};

  for (int kt = 0; kt < 32; ++kt) {
    short8 ka0 = *(const short8*)(wsb + KA_OFF + frag_idx(bh, kt, w, 0, lane));
    short8 ka1 = *(const short8*)(wsb + KA_OFF + frag_idx(bh, kt, w, 1, lane));
    short4v vb[4];
#pragma unroll
    for (int et = 0; et < 4; ++et)
      vb[et] = *(const short4v*)(wsb + VB_OFF + vb_idx(bh, kt, w, et, lane));

#pragma unroll
    for (int nt = 0; nt < 4; ++nt) {
      f32x4 y = (f32x4){0.f, 0.f, 0.f, 0.f};
      y = __builtin_amdgcn_mfma_f32_16x16x32_bf16(ka0, qf[nt][0], y, 0, 0, 0);
      y = __builtin_amdgcn_mfma_f32_16x16x32_bf16(ka1, qf[nt][1], y, 0, 0, 0);
      short4v pa;
#pragma unroll
      for (int r = 0; r < 4; ++r) pa[r] = (short)f2bf(__expf(y[r]));
#pragma unroll
      for (int et = 0; et < 4; ++et)
        oacc[nt][et] = __builtin_amdgcn_mfma_f32_16x16x16bf16_1k(pa, vb[et], oacc[nt][et], 0, 0, 0);
    }
  }

  __shared__ float red[4][64][68];
#pragma unroll
  for (int nt = 0; nt < 4; ++nt)
#pragma unroll
    for (int et = 0; et < 4; ++et)
#pragma unroll
      for (int r = 0; r < 4; ++r)
        red[w][nt * 16 + quad * 4 + r][et * 16 + l16] = oacc[nt][et][r];
  __syncthreads();
  float* og = out + ((size_t)b * LL + qbase + w * 16) * 512 + h * 64;
#pragma unroll
  for (int i = 0; i < 16; ++i) {
    float s = red[0][w * 16 + i][lane] + red[1][w * 16 + i][lane] +
              red[2][w * 16 + i][lane] + red[3][w * 16 + i][lane];
    og[(size_t)i * 512 + lane] = s;
  }
}

extern "C" void kernel_launch(void* const* d_in, const int* in_sizes, int n_in,
                              void* d_out, int out_size, void* d_ws, size_t ws_size,
                              hipStream_t stream) {
  const float* keys    = (const float*)d_in[0];
  const float* queries = (const float*)d_in[1];
  const float* values  = (const float*)d_in[2];
  const float* WQ      = (const float*)d_in[3];
  const float* WK      = (const float*)d_in[4];
  const float* WV      = (const float*)d_in[5];
  float* out = (float*)d_out;
  u16* wsb = (u16*)d_ws;

  prep_kernel<<<dim3(768 + 384), 256, 0, stream>>>(queries, keys, values, WQ, WK, WV, wsb);
  proj_kernel<<<dim3(32, 16, 3), 256, 0, stream>>>(wsb);
  stats_kernel<<<dim3(32, 16), 256, 0, stream>>>(wsb);
  attn_kernel<<<dim3(32, 16), 256, 0, stream>>>(wsb, out);
}